// Round 6
// baseline (369.714 us; speedup 1.0000x reference)
//
#include <hip/hip_runtime.h>
#include <hip/hip_bf16.h>

typedef __hip_bfloat16 bf16;
typedef unsigned short ushort;
typedef unsigned int uint;
typedef __attribute__((ext_vector_type(8))) short short8;
typedef __attribute__((ext_vector_type(4))) float f32x4;

#define Bsz 2
#define Tn  1536
#define Cn  1536
#define Hn  8
#define Kn  64
#define Vn  192
// H*K = 512, H*V = 1536, 2T-1 = 3071

__device__ __forceinline__ ushort f2bs(float f) {
  union { bf16 h; ushort u; } cv;
  cv.h = __float2bfloat16(f);
  return cv.u;
}
__device__ __forceinline__ float bs2f(ushort u) {
  union { float f; uint v; } cv; cv.v = ((uint)u) << 16; return cv.f;
}

// async global->LDS, 16B per lane; LDS dest = wave-uniform base + lane*16
__device__ __forceinline__ void gld_lds16(const ushort* g, ushort* l) {
  __builtin_amdgcn_global_load_lds(
      (const __attribute__((address_space(1))) uint*)g,
      (__attribute__((address_space(3))) uint*)l, 16, 0, 0);
}

// ---------------------------------------------------------------------------
// f32 -> bf16 elementwise (x), vectorized x4
// ---------------------------------------------------------------------------
__global__ __launch_bounds__(256) void cvt_bf16(const float* __restrict__ in,
                                                ushort* __restrict__ out, int n4) {
  int i = blockIdx.x * 256 + threadIdx.x;
  if (i < n4) {
    float4 v = ((const float4*)in)[i];
    uint2 o;
    o.x = (uint)f2bs(v.x) | ((uint)f2bs(v.y) << 16);
    o.y = (uint)f2bs(v.z) | ((uint)f2bs(v.w) << 16);
    ((uint2*)out)[i] = o;
  }
}

// ---------------------------------------------------------------------------
// All four weight transposes in one launch (z selects matrix).
// in f32 [R=1536][Cc] -> out bf16 [Cc][1536]. 32x32 LDS tiles.
// z=0: Wq (Cc=512), z=1: Wk (Cc=512), z=2: Wv (Cc=1536), z=3: Wo (Cc=1536).
// ---------------------------------------------------------------------------
__global__ __launch_bounds__(256) void transp_all(
    const float* __restrict__ Wq, const float* __restrict__ Wk,
    const float* __restrict__ Wv, const float* __restrict__ Wo,
    ushort* __restrict__ Wt, ushort* __restrict__ Wot) {
  const int z = blockIdx.z;
  if (z < 2 && blockIdx.x >= 16) return;
  const float* in = (z == 0) ? Wq : (z == 1) ? Wk : (z == 2) ? Wv : Wo;
  ushort* out = (z == 0) ? Wt : (z == 1) ? Wt + 512 * 1536
              : (z == 2) ? Wt + 1024 * 1536 : Wot;
  const int Cc = (z < 2) ? 512 : 1536;
  __shared__ float tile[32][33];
  const int bx = blockIdx.x * 32;
  const int by = blockIdx.y * 32;
  const int tx = threadIdx.x & 31, ty = threadIdx.x >> 5;
#pragma unroll
  for (int i = 0; i < 32; i += 8)
    tile[ty + i][tx] = in[(size_t)(by + ty + i) * Cc + bx + tx];
  __syncthreads();
#pragma unroll
  for (int i = 0; i < 32; i += 8)
    out[(size_t)(bx + ty + i) * 1536 + by + tx] = f2bs(tile[tx][ty + i]);
}

// ---------------------------------------------------------------------------
// rk[r,c] (bf16) from the Borzoi central-mask basis (double widths; margins
// to integers >= 0.02 so no comparison flips vs the fp32 reference).
// ---------------------------------------------------------------------------
__global__ __launch_bounds__(512) void rk_kernel(const float* __restrict__ Wr,
                                                 ushort* __restrict__ rk) {
  const int r = blockIdx.x;
  const int c = threadIdx.x;
  const float d = (float)(r - (Tn - 1));
  const float ad = fabsf(d);
  const float sg = (d > 0.f) ? 1.f : ((d < 0.f) ? -1.f : 0.f);
  float acc = 0.f;
#pragma unroll
  for (int i = 0; i < 16; i++) {
    double cw = exp(log((double)(Tn + 1)) * (double)(i + 1) / 16.0) - 1.0;
    if ((float)cw > ad) acc += Wr[i * 512 + c] + sg * Wr[(16 + i) * 512 + c];
  }
  rk[(size_t)r * 512 + c] = f2bs(acc);
}

// ---------------------------------------------------------------------------
// Fused QKV MFMA GEMM: xb @ Wt^T-layout -> qb/kb/vtb (m97 structure).
// ---------------------------------------------------------------------------
__global__ __launch_bounds__(256) void gemm_qkv(
    const ushort* __restrict__ xb, const ushort* __restrict__ Wt,
    ushort* __restrict__ qb, ushort* __restrict__ kb, ushort* __restrict__ vtb) {
  __shared__ ushort Al[128 * 32];
  __shared__ ushort Bl[128 * 32];
  const int tid = threadIdx.x;
  const int w = tid >> 6, lane = tid & 63, quad = lane >> 4, ln = lane & 15;
  const int bm = blockIdx.y * 128, bn = blockIdx.x * 128;
  const int wm = (w & 1) * 64, wn = (w >> 1) * 64;
  f32x4 acc[4][4];
#pragma unroll
  for (int i = 0; i < 4; i++)
#pragma unroll
    for (int j = 0; j < 4; j++) acc[i][j] = (f32x4){0.f, 0.f, 0.f, 0.f};

  for (int k0 = 0; k0 < 1536; k0 += 32) {
    __syncthreads();
#pragma unroll
    for (int st = 0; st < 2; st++) {
      int idx = tid + st * 256;
      int row = idx >> 2, col = (idx & 3) * 8;
      gld_lds16(xb + (size_t)(bm + row) * 1536 + k0 + col, Al + idx * 8);
      gld_lds16(Wt + (size_t)(bn + row) * 1536 + k0 + col, Bl + idx * 8);
    }
    __syncthreads();
    short8 af[4], bfr[4];
#pragma unroll
    for (int t = 0; t < 4; t++) {
      af[t]  = *(const short8*)(Al + (wm + t * 16 + ln) * 32 + quad * 8);
      bfr[t] = *(const short8*)(Bl + (wn + t * 16 + ln) * 32 + quad * 8);
    }
#pragma unroll
    for (int mt = 0; mt < 4; mt++)
#pragma unroll
      for (int nt = 0; nt < 4; nt++)
        acc[mt][nt] = __builtin_amdgcn_mfma_f32_16x16x32_bf16(
            af[mt], bfr[nt], acc[mt][nt], 0, 0, 0);
  }

  if (bn < 512) {
#pragma unroll
    for (int mt = 0; mt < 4; mt++)
#pragma unroll
      for (int nt = 0; nt < 4; nt++)
#pragma unroll
        for (int r = 0; r < 4; r++) {
          int m = bm + wm + mt * 16 + quad * 4 + r;
          int n = bn + wn + nt * 16 + ln;
          qb[(size_t)m * 512 + n] = f2bs(acc[mt][nt][r] * 0.125f);
        }
  } else if (bn < 1024) {
#pragma unroll
    for (int mt = 0; mt < 4; mt++)
#pragma unroll
      for (int nt = 0; nt < 4; nt++)
#pragma unroll
        for (int r = 0; r < 4; r++) {
          int m = bm + wm + mt * 16 + quad * 4 + r;
          int n = bn - 512 + wn + nt * 16 + ln;
          kb[(size_t)m * 512 + n] = f2bs(acc[mt][nt][r]);
        }
  } else {
#pragma unroll
    for (int mt = 0; mt < 4; mt++)
#pragma unroll
      for (int nt = 0; nt < 4; nt++) {
        int vcol = bn - 1024 + wn + nt * 16 + ln;
        int m0 = bm + wm + mt * 16 + quad * 4;
        uint2 val;
        val.x = (uint)f2bs(acc[mt][nt][0]) | ((uint)f2bs(acc[mt][nt][1]) << 16);
        val.y = (uint)f2bs(acc[mt][nt][2]) | ((uint)f2bs(acc[mt][nt][3]) << 16);
        *(uint2*)(vtb + (size_t)vcol * 3072 + m0) = val;
      }
  }
}

// ---------------------------------------------------------------------------
// Output MFMA GEMM: att(bf16) @ Wot + bo -> f32 out.
// ---------------------------------------------------------------------------
__global__ __launch_bounds__(256) void gemm_out(
    const ushort* __restrict__ att, const ushort* __restrict__ Wot,
    const float* __restrict__ bo, float* __restrict__ out) {
  __shared__ ushort Al[128 * 32];
  __shared__ ushort Bl[128 * 32];
  const int tid = threadIdx.x;
  const int w = tid >> 6, lane = tid & 63, quad = lane >> 4, ln = lane & 15;
  const int bm = blockIdx.y * 128, bn = blockIdx.x * 128;
  const int wm = (w & 1) * 64, wn = (w >> 1) * 64;
  f32x4 acc[4][4];
#pragma unroll
  for (int i = 0; i < 4; i++)
#pragma unroll
    for (int j = 0; j < 4; j++) acc[i][j] = (f32x4){0.f, 0.f, 0.f, 0.f};

  for (int k0 = 0; k0 < 1536; k0 += 32) {
    __syncthreads();
#pragma unroll
    for (int st = 0; st < 2; st++) {
      int idx = tid + st * 256;
      int row = idx >> 2, col = (idx & 3) * 8;
      gld_lds16(att + (size_t)(bm + row) * 1536 + k0 + col, Al + idx * 8);
      gld_lds16(Wot + (size_t)(bn + row) * 1536 + k0 + col, Bl + idx * 8);
    }
    __syncthreads();
    short8 af[4], bfr[4];
#pragma unroll
    for (int t = 0; t < 4; t++) {
      af[t]  = *(const short8*)(Al + (wm + t * 16 + ln) * 32 + quad * 8);
      bfr[t] = *(const short8*)(Bl + (wn + t * 16 + ln) * 32 + quad * 8);
    }
#pragma unroll
    for (int mt = 0; mt < 4; mt++)
#pragma unroll
      for (int nt = 0; nt < 4; nt++)
        acc[mt][nt] = __builtin_amdgcn_mfma_f32_16x16x32_bf16(
            af[mt], bfr[nt], acc[mt][nt], 0, 0, 0);
  }
#pragma unroll
  for (int mt = 0; mt < 4; mt++)
#pragma unroll
    for (int nt = 0; nt < 4; nt++)
#pragma unroll
      for (int r = 0; r < 4; r++) {
        int m = bm + wm + mt * 16 + quad * 4 + r;
        int n = bn + wn + nt * 16 + ln;
        out[(size_t)m * 1536 + n] = acc[mt][nt][r] + bo[n];
      }
}

// ---------------------------------------------------------------------------
// MFMA flash attention, split-K(x2), t-tile 64, 4 waves — ZERO barriers.
// B-fragments (K, rk, V) are loaded directly from global (L2/L3-resident);
// no LDS staging at all. LDS holds only per-wave scratch:
//   prl f32[16][84] (rel logits, C->gather) overlaid by Pp bf16[16][72]
//   (probs, C-layout -> A-layout round trip). Same-wave RAW via lgkmcnt.
// Rel: j = (s-s0)-(t-t0)+63; wave w covers j-tiles 3-w..7-w (5 tiles).
// Partials: normalized O (bf16) + (m,l) per row; combined by attn_combine.
// ---------------------------------------------------------------------------
__global__ __launch_bounds__(256, 3) void attn_mfma(
    const ushort* __restrict__ qb, const ushort* __restrict__ kb,
    const ushort* __restrict__ vtb, const ushort* __restrict__ rkb,
    const float* __restrict__ rwb, const float* __restrict__ rrb,
    ushort* __restrict__ op0, ushort* __restrict__ op1,
    float2* __restrict__ mlb) {
  __shared__ __align__(16) char smem[21504];

  const int t0 = blockIdx.x * 64;
  const int h  = blockIdx.y;
  const int b  = blockIdx.z >> 1;
  const int sk = blockIdx.z & 1;
  const int bT = b * Tn;
  const int tid = threadIdx.x;
  const int w = tid >> 6, lane = tid & 63, quad = lane >> 4, ln = lane & 15;

  float*  prl = (float*)(smem + w * 5376);   // [16][84] f32
  ushort* Pp  = (ushort*)(smem + w * 5376);  // [16][72] bf16 (overlay)

  // Q fragments (A-layout m=ln, k=quad*8+ks*32+e), + biases
  short8 qw8[2], qr8[2];
  {
    const ushort* qrow = qb + (size_t)(bT + t0 + 16 * w + ln) * 512 + h * 64;
#pragma unroll
    for (int ks = 0; ks < 2; ks++) {
      int k0 = quad * 8 + ks * 32;
#pragma unroll
      for (int e = 0; e < 8; e++) {
        float qv = bs2f(qrow[k0 + e]);
        qw8[ks][e] = (short)f2bs(qv + rwb[h * 64 + k0 + e]);
        qr8[ks][e] = (short)f2bs(qv + rrb[h * 64 + k0 + e]);
      }
    }
  }

  // per-wave-invariant pieces of the B-frag addresses
  const ushort* kbase  = kb + (size_t)(bT)*512 + h * 64 + quad * 8;
  const ushort* rkbase = rkb + h * 64 + quad * 8;
  const ushort* vbase  = vtb + (size_t)(h * 192 + ln) * 3072 + bT + quad * 8;

  f32x4 Oacc[12];
  float m_i[4], l_i[4];
#pragma unroll
  for (int vt = 0; vt < 12; vt++) Oacc[vt] = (f32x4){0.f, 0.f, 0.f, 0.f};
#pragma unroll
  for (int r = 0; r < 4; r++) { m_i[r] = -1e30f; l_i[r] = 0.f; }

  for (int ch = 0; ch < 12; ch++) {
    const int s0 = sk * 768 + ch * 64;
    const int Dbase = s0 - t0 + 1472;

    // ---- S phase: B-frags straight from global ----
    f32x4 Sacc[4], Pacc[5];
#pragma unroll
    for (int ct = 0; ct < 4; ct++) {
      Sacc[ct] = (f32x4){0.f, 0.f, 0.f, 0.f};
#pragma unroll
      for (int ks = 0; ks < 2; ks++) {
        short8 bfr = *(const short8*)(
            kbase + (size_t)(s0 + 16 * ct + ln) * 512 + ks * 32);
        Sacc[ct] = __builtin_amdgcn_mfma_f32_16x16x32_bf16(qw8[ks], bfr, Sacc[ct], 0, 0, 0);
      }
    }
#pragma unroll
    for (int jtl = 0; jtl < 5; jtl++) {
      int jt = 3 - w + jtl;
      int jr = Dbase + 16 * jt + ln; jr = jr > 3070 ? 3070 : jr;
      Pacc[jtl] = (f32x4){0.f, 0.f, 0.f, 0.f};
#pragma unroll
      for (int ks = 0; ks < 2; ks++) {
        short8 bfr = *(const short8*)(rkbase + (size_t)jr * 512 + ks * 32);
        Pacc[jtl] = __builtin_amdgcn_mfma_f32_16x16x32_bf16(qr8[ks], bfr, Pacc[jtl], 0, 0, 0);
      }
    }
    // rel logits (C-layout) -> per-wave prl; local col jl = 16*jtl + ln
#pragma unroll
    for (int jtl = 0; jtl < 5; jtl++)
#pragma unroll
      for (int r = 0; r < 4; r++)
        prl[(4 * quad + r) * 84 + 16 * jtl + ln] = Pacc[jtl][r];
    __asm__ volatile("s_waitcnt lgkmcnt(0)" ::: "memory");

    // gather: jl = 16ct + ln - row + 15 (row = wave-local q-row)
    float pS[4][4];
#pragma unroll
    for (int ct = 0; ct < 4; ct++)
#pragma unroll
      for (int r = 0; r < 4; r++) {
        int row = 4 * quad + r;
        pS[ct][r] = Sacc[ct][r] + prl[row * 84 + 16 * ct + ln - row + 15];
      }
    // online softmax (row lives in the 16 lanes of this quad)
    float alpha[4];
#pragma unroll
    for (int r = 0; r < 4; r++) {
      float mx = fmaxf(fmaxf(pS[0][r], pS[1][r]), fmaxf(pS[2][r], pS[3][r]));
#pragma unroll
      for (int off = 8; off >= 1; off >>= 1) mx = fmaxf(mx, __shfl_xor(mx, off));
      float mnew = fmaxf(m_i[r], mx);
      alpha[r] = __expf(m_i[r] - mnew);
      m_i[r] = mnew;
      float rs = 0.f;
#pragma unroll
      for (int ct = 0; ct < 4; ct++) {
        pS[ct][r] = __expf(pS[ct][r] - mnew);
        rs += pS[ct][r];
      }
#pragma unroll
      for (int off = 8; off >= 1; off >>= 1) rs += __shfl_xor(rs, off);
      l_i[r] = l_i[r] * alpha[r] + rs;
    }
#pragma unroll
    for (int vt = 0; vt < 12; vt++)
#pragma unroll
      for (int r = 0; r < 4; r++) Oacc[vt][r] *= alpha[r];
    // probs -> Pp (bf16, overlays prl; all prl reads precede, same wave = safe)
#pragma unroll
    for (int ct = 0; ct < 4; ct++)
#pragma unroll
      for (int r = 0; r < 4; r++)
        Pp[(4 * quad + r) * 72 + 16 * ct + ln] = f2bs(pS[ct][r]);
    __asm__ volatile("s_waitcnt lgkmcnt(0)" ::: "memory");

    // ---- PV phase: V B-frags straight from global ----
    short8 afr[2];
#pragma unroll
    for (int ks = 0; ks < 2; ks++)
      afr[ks] = *(const short8*)(Pp + ln * 72 + quad * 8 + ks * 32);
#pragma unroll
    for (int vt = 0; vt < 12; vt++) {
#pragma unroll
      for (int ks = 0; ks < 2; ks++) {
        short8 bfr = *(const short8*)(
            vbase + (size_t)(16 * vt) * 3072 + s0 + ks * 32);
        Oacc[vt] = __builtin_amdgcn_mfma_f32_16x16x32_bf16(afr[ks], bfr, Oacc[vt], 0, 0, 0);
      }
    }
  }

  // epilogue: normalized bf16 partial + (m,l)
  ushort* op = sk ? op1 : op0;
  float inv[4];
#pragma unroll
  for (int r = 0; r < 4; r++) inv[r] = 1.f / l_i[r];
#pragma unroll
  for (int vt = 0; vt < 12; vt++)
#pragma unroll
    for (int r = 0; r < 4; r++) {
      int t = t0 + 16 * w + 4 * quad + r;
      op[(size_t)(bT + t) * 1536 + h * 192 + 16 * vt + ln] = f2bs(Oacc[vt][r] * inv[r]);
    }
  if (ln == 0) {
#pragma unroll
    for (int r = 0; r < 4; r++) {
      int t = t0 + 16 * w + 4 * quad + r;
      float2 v; v.x = m_i[r]; v.y = l_i[r];
      mlb[((sk * 2 + b) * 8 + h) * 1536 + t] = v;
    }
  }
}

// ---------------------------------------------------------------------------
// Combine the two split-K partials: O = sum_i e^{m_i-M} l_i O_i / sum e^{m-M} l
// ---------------------------------------------------------------------------
__global__ __launch_bounds__(256) void attn_combine(
    const ushort* __restrict__ op0, const ushort* __restrict__ op1,
    const float2* __restrict__ mlb, ushort* __restrict__ att) {
  int g = blockIdx.x * 256 + threadIdx.x;   // group of 4 bf16
  int row = g / 384;                        // 0..3071
  int c4 = (g - row * 384) * 4;             // 0..1532
  int b = row >> 11 ? 1 : (row >= 1536);    // row/1536 (row<3072)
  int t = row - b * 1536;
  int h = c4 / 192;
  float2 ml0 = mlb[((0 + b) * 8 + h) * 1536 + t];
  float2 ml1 = mlb[((2 + b) * 8 + h) * 1536 + t];
  float M = fmaxf(ml0.x, ml1.x);
  float w0 = __expf(ml0.x - M) * ml0.y;
  float w1 = __expf(ml1.x - M) * ml1.y;
  float inv = 1.f / (w0 + w1);
  w0 *= inv; w1 *= inv;
  size_t off = (size_t)row * 1536 + c4;
  uint2 a = *(const uint2*)(op0 + off);
  uint2 c = *(const uint2*)(op1 + off);
  uint2 o;
  float r0 = w0 * bs2f((ushort)(a.x & 0xffff)) + w1 * bs2f((ushort)(c.x & 0xffff));
  float r1 = w0 * bs2f((ushort)(a.x >> 16))    + w1 * bs2f((ushort)(c.x >> 16));
  float r2 = w0 * bs2f((ushort)(a.y & 0xffff)) + w1 * bs2f((ushort)(c.y & 0xffff));
  float r3 = w0 * bs2f((ushort)(a.y >> 16))    + w1 * bs2f((ushort)(c.y >> 16));
  o.x = (uint)f2bs(r0) | ((uint)f2bs(r1) << 16);
  o.y = (uint)f2bs(r2) | ((uint)f2bs(r3) << 16);
  *(uint2*)(att + off) = o;
}

// ---------------------------------------------------------------------------
extern "C" void kernel_launch(void* const* d_in, const int* in_sizes, int n_in,
                              void* d_out, int out_size, void* d_ws, size_t ws_size,
                              hipStream_t stream) {
  const float* x   = (const float*)d_in[0];
  const float* Wq  = (const float*)d_in[1];
  const float* Wk  = (const float*)d_in[2];
  const float* Wv  = (const float*)d_in[3];
  const float* Wr  = (const float*)d_in[4];
  const float* rwb = (const float*)d_in[5];
  const float* rrb = (const float*)d_in[6];
  const float* Wo  = (const float*)d_in[7];
  const float* bo  = (const float*)d_in[8];
  float* out = (float*)d_out;

  char* ws = (char*)d_ws;
  // Region A [0, 9437184): xb (cvt->qkv) -> op1 (attn) -> att (combine, same
  // addresses elementwise) -> gemm_out input.
  ushort* xb  = (ushort*)ws;
  ushort* op1 = (ushort*)ws;
  ushort* att = (ushort*)ws;
  ushort* Wot = (ushort*)(ws + 9437184);    // [1536][1536] bf16, until gemm_out
  ushort* Wt  = (ushort*)(ws + 14155776);   // [2560][1536] bf16, until gemm_qkv
  ushort* op0 = (ushort*)(ws + 14155776);   // overlays dead Wt (attn phase)
  ushort* qb  = (ushort*)(ws + 23592960);   // [3072][512] bf16 (scaled)
  ushort* kb  = (ushort*)(ws + 26738688);   // [3072][512] bf16
  ushort* vtb = (ushort*)(ws + 29884416);   // [1536][3072] bf16 (V^T)
  ushort* rkb = (ushort*)(ws + 39321600);   // [3071][512] bf16
  float2* mlb = (float2*)(ws + 42467328);   // [2][2][8][1536] (m,l)

  cvt_bf16<<<dim3(4608), dim3(256), 0, stream>>>(x, xb, 3072 * 1536 / 4);
  transp_all<<<dim3(48, 48, 4), dim3(256), 0, stream>>>(Wq, Wk, Wv, Wo, Wt, Wot);
  rk_kernel<<<dim3(2 * Tn - 1), dim3(512), 0, stream>>>(Wr, rkb);
  gemm_qkv<<<dim3(20, 24), dim3(256), 0, stream>>>(xb, Wt, qb, kb, vtb);
  attn_mfma<<<dim3(24, 8, 4), dim3(256), 0, stream>>>(
      qb, kb, vtb, rkb, rwb, rrb, op0, op1, mlb);
  attn_combine<<<dim3(4608), dim3(256), 0, stream>>>(op0, op1, mlb, att);
  gemm_out<<<dim3(12, 24), dim3(256), 0, stream>>>(att, Wot, bo, out);
}

// Round 7
// 314.775 us; speedup vs baseline: 1.1745x; 1.1745x over previous
//
#include <hip/hip_runtime.h>
#include <hip/hip_bf16.h>

typedef __hip_bfloat16 bf16;
typedef unsigned short ushort;
typedef unsigned int uint;
typedef __attribute__((ext_vector_type(8))) short short8;
typedef __attribute__((ext_vector_type(4))) float f32x4;

#define Bsz 2
#define Tn  1536
#define Cn  1536
#define Hn  8
#define Kn  64
#define Vn  192
// H*K = 512, H*V = 1536, 2T-1 = 3071

__device__ __forceinline__ ushort f2bs(float f) {
  union { bf16 h; ushort u; } cv;
  cv.h = __float2bfloat16(f);
  return cv.u;
}
__device__ __forceinline__ float bs2f(ushort u) {
  union { float f; uint v; } cv; cv.v = ((uint)u) << 16; return cv.f;
}

// async global->LDS, 16B per lane; LDS dest = wave-uniform base + lane*16
__device__ __forceinline__ void gld_lds16(const ushort* g, ushort* l) {
  __builtin_amdgcn_global_load_lds(
      (const __attribute__((address_space(1))) uint*)g,
      (__attribute__((address_space(3))) uint*)l, 16, 0, 0);
}

// ---------------------------------------------------------------------------
// Merged prep kernel, grid (48,48,6):
//  z=0..3: transpose+cvt  W{q,k,v,o} f32 [1536][Cc] -> bf16 [Cc][1536]
//  z=4   : x f32 -> xb bf16 (vectorized x4, 2 grid-stride iters)
//  z=5   : rk[r,c] bf16 from the Borzoi central-mask basis (double widths;
//          margins to integers >= 0.02 so no comparison flips vs fp32 ref).
// ---------------------------------------------------------------------------
__global__ __launch_bounds__(256) void prep(
    const float* __restrict__ x,  const float* __restrict__ Wq,
    const float* __restrict__ Wk, const float* __restrict__ Wv,
    const float* __restrict__ Wo, const float* __restrict__ Wr,
    ushort* __restrict__ xb, ushort* __restrict__ Wt,
    ushort* __restrict__ Wot, ushort* __restrict__ rkb) {
  const int z = blockIdx.z;
  if (z < 4) {
    if (z < 2 && blockIdx.x >= 16) return;
    const float* in = (z == 0) ? Wq : (z == 1) ? Wk : (z == 2) ? Wv : Wo;
    ushort* out = (z == 0) ? Wt : (z == 1) ? Wt + 512 * 1536
                : (z == 2) ? Wt + 1024 * 1536 : Wot;
    const int Cc = (z < 2) ? 512 : 1536;
    __shared__ float tile[32][33];
    const int bx = blockIdx.x * 32;
    const int by = blockIdx.y * 32;
    const int tx = threadIdx.x & 31, ty = threadIdx.x >> 5;
#pragma unroll
    for (int i = 0; i < 32; i += 8)
      tile[ty + i][tx] = in[(size_t)(by + ty + i) * Cc + bx + tx];
    __syncthreads();
#pragma unroll
    for (int i = 0; i < 32; i += 8)
      out[(size_t)(bx + ty + i) * 1536 + by + tx] = f2bs(tile[tx][ty + i]);
  } else if (z == 4) {
    const int n4 = 3072 * 1536 / 4;
    for (int i = (blockIdx.y * 48 + blockIdx.x) * 256 + threadIdx.x; i < n4;
         i += 2304 * 256) {
      float4 v = ((const float4*)x)[i];
      uint2 o;
      o.x = (uint)f2bs(v.x) | ((uint)f2bs(v.y) << 16);
      o.y = (uint)f2bs(v.z) | ((uint)f2bs(v.w) << 16);
      ((uint2*)xb)[i] = o;
    }
  } else {
    for (int u = blockIdx.y * 48 + blockIdx.x; u < 2 * 3071; u += 2304) {
      const int r = u >> 1;
      const int c = (u & 1) * 256 + threadIdx.x;
      const float d = (float)(r - (Tn - 1));
      const float ad = fabsf(d);
      const float sg = (d > 0.f) ? 1.f : ((d < 0.f) ? -1.f : 0.f);
      float acc = 0.f;
#pragma unroll
      for (int i = 0; i < 16; i++) {
        double cw = exp(log((double)(Tn + 1)) * (double)(i + 1) / 16.0) - 1.0;
        if ((float)cw > ad) acc += Wr[i * 512 + c] + sg * Wr[(16 + i) * 512 + c];
      }
      rkb[(size_t)r * 512 + c] = f2bs(acc);
    }
  }
}

// ---------------------------------------------------------------------------
// Fused QKV MFMA GEMM: xb @ Wt^T-layout -> qb/kb/vtb (m97 structure).
// ---------------------------------------------------------------------------
__global__ __launch_bounds__(256) void gemm_qkv(
    const ushort* __restrict__ xb, const ushort* __restrict__ Wt,
    ushort* __restrict__ qb, ushort* __restrict__ kb, ushort* __restrict__ vtb) {
  __shared__ ushort Al[128 * 32];
  __shared__ ushort Bl[128 * 32];
  const int tid = threadIdx.x;
  const int w = tid >> 6, lane = tid & 63, quad = lane >> 4, ln = lane & 15;
  const int bm = blockIdx.y * 128, bn = blockIdx.x * 128;
  const int wm = (w & 1) * 64, wn = (w >> 1) * 64;
  f32x4 acc[4][4];
#pragma unroll
  for (int i = 0; i < 4; i++)
#pragma unroll
    for (int j = 0; j < 4; j++) acc[i][j] = (f32x4){0.f, 0.f, 0.f, 0.f};

  for (int k0 = 0; k0 < 1536; k0 += 32) {
    __syncthreads();
#pragma unroll
    for (int st = 0; st < 2; st++) {
      int idx = tid + st * 256;
      int row = idx >> 2, col = (idx & 3) * 8;
      gld_lds16(xb + (size_t)(bm + row) * 1536 + k0 + col, Al + idx * 8);
      gld_lds16(Wt + (size_t)(bn + row) * 1536 + k0 + col, Bl + idx * 8);
    }
    __syncthreads();
    short8 af[4], bfr[4];
#pragma unroll
    for (int t = 0; t < 4; t++) {
      af[t]  = *(const short8*)(Al + (wm + t * 16 + ln) * 32 + quad * 8);
      bfr[t] = *(const short8*)(Bl + (wn + t * 16 + ln) * 32 + quad * 8);
    }
#pragma unroll
    for (int mt = 0; mt < 4; mt++)
#pragma unroll
      for (int nt = 0; nt < 4; nt++)
        acc[mt][nt] = __builtin_amdgcn_mfma_f32_16x16x32_bf16(
            af[mt], bfr[nt], acc[mt][nt], 0, 0, 0);
  }

  if (bn < 512) {
#pragma unroll
    for (int mt = 0; mt < 4; mt++)
#pragma unroll
      for (int nt = 0; nt < 4; nt++)
#pragma unroll
        for (int r = 0; r < 4; r++) {
          int m = bm + wm + mt * 16 + quad * 4 + r;
          int n = bn + wn + nt * 16 + ln;
          qb[(size_t)m * 512 + n] = f2bs(acc[mt][nt][r] * 0.125f);
        }
  } else if (bn < 1024) {
#pragma unroll
    for (int mt = 0; mt < 4; mt++)
#pragma unroll
      for (int nt = 0; nt < 4; nt++)
#pragma unroll
        for (int r = 0; r < 4; r++) {
          int m = bm + wm + mt * 16 + quad * 4 + r;
          int n = bn - 512 + wn + nt * 16 + ln;
          kb[(size_t)m * 512 + n] = f2bs(acc[mt][nt][r]);
        }
  } else {
#pragma unroll
    for (int mt = 0; mt < 4; mt++)
#pragma unroll
      for (int nt = 0; nt < 4; nt++) {
        int vcol = bn - 1024 + wn + nt * 16 + ln;
        int m0 = bm + wm + mt * 16 + quad * 4;
        uint2 val;
        val.x = (uint)f2bs(acc[mt][nt][0]) | ((uint)f2bs(acc[mt][nt][1]) << 16);
        val.y = (uint)f2bs(acc[mt][nt][2]) | ((uint)f2bs(acc[mt][nt][3]) << 16);
        *(uint2*)(vtb + (size_t)vcol * 3072 + m0) = val;
      }
  }
}

// ---------------------------------------------------------------------------
// Output MFMA GEMM: att(bf16) @ Wot + bo -> f32 out.
// ---------------------------------------------------------------------------
__global__ __launch_bounds__(256) void gemm_out(
    const ushort* __restrict__ att, const ushort* __restrict__ Wot,
    const float* __restrict__ bo, float* __restrict__ out) {
  __shared__ ushort Al[128 * 32];
  __shared__ ushort Bl[128 * 32];
  const int tid = threadIdx.x;
  const int w = tid >> 6, lane = tid & 63, quad = lane >> 4, ln = lane & 15;
  const int bm = blockIdx.y * 128, bn = blockIdx.x * 128;
  const int wm = (w & 1) * 64, wn = (w >> 1) * 64;
  f32x4 acc[4][4];
#pragma unroll
  for (int i = 0; i < 4; i++)
#pragma unroll
    for (int j = 0; j < 4; j++) acc[i][j] = (f32x4){0.f, 0.f, 0.f, 0.f};

  for (int k0 = 0; k0 < 1536; k0 += 32) {
    __syncthreads();
#pragma unroll
    for (int st = 0; st < 2; st++) {
      int idx = tid + st * 256;
      int row = idx >> 2, col = (idx & 3) * 8;
      gld_lds16(att + (size_t)(bm + row) * 1536 + k0 + col, Al + idx * 8);
      gld_lds16(Wot + (size_t)(bn + row) * 1536 + k0 + col, Bl + idx * 8);
    }
    __syncthreads();
    short8 af[4], bfr[4];
#pragma unroll
    for (int t = 0; t < 4; t++) {
      af[t]  = *(const short8*)(Al + (wm + t * 16 + ln) * 32 + quad * 8);
      bfr[t] = *(const short8*)(Bl + (wn + t * 16 + ln) * 32 + quad * 8);
    }
#pragma unroll
    for (int mt = 0; mt < 4; mt++)
#pragma unroll
      for (int nt = 0; nt < 4; nt++)
        acc[mt][nt] = __builtin_amdgcn_mfma_f32_16x16x32_bf16(
            af[mt], bfr[nt], acc[mt][nt], 0, 0, 0);
  }
#pragma unroll
  for (int mt = 0; mt < 4; mt++)
#pragma unroll
    for (int nt = 0; nt < 4; nt++)
#pragma unroll
      for (int r = 0; r < 4; r++) {
        int m = bm + wm + mt * 16 + quad * 4 + r;
        int n = bn + wn + nt * 16 + ln;
        out[(size_t)m * 1536 + n] = acc[mt][nt][r] + bo[n];
      }
}

// ---------------------------------------------------------------------------
// MFMA flash attention, split-K(x2), t-tile 64, 4 waves, DMA staging.
// (r5 structure — proven 76us — with bf16 prl scratch and 4 blocks/CU.)
// Block = (t-tile 24, h 8, b*2+sk 4). Each wave owns 16 q-rows.
// LDS [38912B]: K[64]x128B @0, RK[128]x128B @8192 (V[192]x128B overlays both);
//   per-wave 3584B scratch @24576: prl bf16[16][104] overlaid by Pp bf16[16][72].
// XOR swizzle: 16B chunk c of row r stored at physical chunk c^(r&7).
// Rel: j = (s-s0)-(t-t0)+63 in [0,127); wave w needs j-tiles 3-w..7-w (5).
// Partials: normalized O (bf16) + (m,l) per row; combined by attn_combine.
// ---------------------------------------------------------------------------
__global__ __launch_bounds__(256, 4) void attn_mfma(
    const ushort* __restrict__ qb, const ushort* __restrict__ kb,
    const ushort* __restrict__ vtb, const ushort* __restrict__ rkb,
    const float* __restrict__ rwb, const float* __restrict__ rrb,
    ushort* __restrict__ op0, ushort* __restrict__ op1,
    float2* __restrict__ mlb) {
  __shared__ __align__(16) char smem[38912];
  ushort* Kl  = (ushort*)smem;              // [64] rows x 128B
  ushort* RKl = (ushort*)(smem + 8192);     // [128] rows x 128B
  ushort* Vl  = (ushort*)smem;              // [192] rows x 128B (overlay)

  const int t0 = blockIdx.x * 64;
  const int h  = blockIdx.y;
  const int b  = blockIdx.z >> 1;
  const int sk = blockIdx.z & 1;
  const int bT = b * Tn;
  const int tid = threadIdx.x;
  const int w = tid >> 6, lane = tid & 63, quad = lane >> 4, ln = lane & 15;

  ushort* prlb = (ushort*)(smem + 24576 + w * 3584);  // [16][104] bf16
  ushort* Pp   = (ushort*)(smem + 24576 + w * 3584);  // [16][72] bf16 (overlay)

  const int lr  = lane >> 3;          // staging: row-in-chunk 0..7
  const int lcx = (lane & 7) ^ lr;    // staging: logical 16B chunk (swizzle)

  // Q fragments (A-layout m=ln, k=quad*8+ks*32+e), + biases
  short8 qw8[2], qr8[2];
  {
    const ushort* qrow = qb + (size_t)(bT + t0 + 16 * w + ln) * 512 + h * 64;
#pragma unroll
    for (int ks = 0; ks < 2; ks++) {
      int k0 = quad * 8 + ks * 32;
#pragma unroll
      for (int e = 0; e < 8; e++) {
        float qv = bs2f(qrow[k0 + e]);
        qw8[ks][e] = (short)f2bs(qv + rwb[h * 64 + k0 + e]);
        qr8[ks][e] = (short)f2bs(qv + rrb[h * 64 + k0 + e]);
      }
    }
  }

  f32x4 Oacc[12];
  float m_i[4], l_i[4];
#pragma unroll
  for (int vt = 0; vt < 12; vt++) Oacc[vt] = (f32x4){0.f, 0.f, 0.f, 0.f};
#pragma unroll
  for (int r = 0; r < 4; r++) { m_i[r] = -1e30f; l_i[r] = 0.f; }

  for (int ch = 0; ch < 12; ch++) {
    const int s0 = sk * 768 + ch * 64;
    const int Dbase = s0 - t0 + 1472;
    __syncthreads();   // prev PV done reading Vl (overlay with K/RK)
    // stage K (8 KB, 8 chunks of 1KB; 2 per wave)
#pragma unroll
    for (int i = 0; i < 2; i++) {
      int kc = w * 2 + i, sr = kc * 8 + lr;
      gld_lds16(kb + (size_t)(bT + s0 + sr) * 512 + h * 64 + lcx * 8,
                (ushort*)(smem + kc * 1024) + lane * 8);
    }
    // stage RK (16 KB, 16 chunks; 4 per wave). j=127 unused -> clamp.
#pragma unroll
    for (int i = 0; i < 4; i++) {
      int kc = w * 4 + i, j = kc * 8 + lr;
      int jr = Dbase + j; jr = jr > 3070 ? 3070 : jr;
      gld_lds16(rkb + (size_t)jr * 512 + h * 64 + lcx * 8,
                (ushort*)(smem + 8192 + kc * 1024) + lane * 8);
    }
    __syncthreads();

    // ---- S phase ----
    f32x4 Sacc[4], Pacc[5];
#pragma unroll
    for (int ct = 0; ct < 4; ct++) {
      Sacc[ct] = (f32x4){0.f, 0.f, 0.f, 0.f};
#pragma unroll
      for (int ks = 0; ks < 2; ks++) {
        short8 bfr = *(const short8*)(
            Kl + (16 * ct + ln) * 64 + ((quad + 4 * ks) ^ (ln & 7)) * 8);
        Sacc[ct] = __builtin_amdgcn_mfma_f32_16x16x32_bf16(qw8[ks], bfr, Sacc[ct], 0, 0, 0);
      }
    }
#pragma unroll
    for (int jtl = 0; jtl < 5; jtl++) {
      int jt = 3 - w + jtl;
      Pacc[jtl] = (f32x4){0.f, 0.f, 0.f, 0.f};
#pragma unroll
      for (int ks = 0; ks < 2; ks++) {
        short8 bfr = *(const short8*)(
            RKl + (16 * jt + ln) * 64 + ((quad + 4 * ks) ^ (ln & 7)) * 8);
        Pacc[jtl] = __builtin_amdgcn_mfma_f32_16x16x32_bf16(qr8[ks], bfr, Pacc[jtl], 0, 0, 0);
      }
    }
    // rel logits (C-layout) -> per-wave prl (bf16); local col jl = 16*jtl + ln
#pragma unroll
    for (int jtl = 0; jtl < 5; jtl++)
#pragma unroll
      for (int r = 0; r < 4; r++)
        prlb[(4 * quad + r) * 104 + 16 * jtl + ln] = f2bs(Pacc[jtl][r]);
    __asm__ volatile("s_waitcnt lgkmcnt(0)" ::: "memory");

    // gather: jl = 16ct + ln - row + 15 (row = wave-local q-row)
    float pS[4][4];
#pragma unroll
    for (int ct = 0; ct < 4; ct++)
#pragma unroll
      for (int r = 0; r < 4; r++) {
        int row = 4 * quad + r;
        pS[ct][r] = Sacc[ct][r] + bs2f(prlb[row * 104 + 16 * ct + ln - row + 15]);
      }
    // online softmax (row lives in the 16 lanes of this quad)
    float alpha[4];
#pragma unroll
    for (int r = 0; r < 4; r++) {
      float mx = fmaxf(fmaxf(pS[0][r], pS[1][r]), fmaxf(pS[2][r], pS[3][r]));
#pragma unroll
      for (int off = 8; off >= 1; off >>= 1) mx = fmaxf(mx, __shfl_xor(mx, off));
      float mnew = fmaxf(m_i[r], mx);
      alpha[r] = __expf(m_i[r] - mnew);
      m_i[r] = mnew;
      float rs = 0.f;
#pragma unroll
      for (int ct = 0; ct < 4; ct++) {
        pS[ct][r] = __expf(pS[ct][r] - mnew);
        rs += pS[ct][r];
      }
#pragma unroll
      for (int off = 8; off >= 1; off >>= 1) rs += __shfl_xor(rs, off);
      l_i[r] = l_i[r] * alpha[r] + rs;
    }
#pragma unroll
    for (int vt = 0; vt < 12; vt++)
#pragma unroll
      for (int r = 0; r < 4; r++) Oacc[vt][r] *= alpha[r];
    // probs -> Pp (bf16, overlays prl; all prl reads precede, same wave = safe)
#pragma unroll
    for (int ct = 0; ct < 4; ct++)
#pragma unroll
      for (int r = 0; r < 4; r++)
        Pp[(4 * quad + r) * 72 + 16 * ct + ln] = f2bs(pS[ct][r]);

    __syncthreads();   // all waves done with K/RK
    // stage V (24 KB, 24 chunks; 6 per wave) over K+RK region
#pragma unroll
    for (int i = 0; i < 6; i++) {
      int kc = w * 6 + i, vr = kc * 8 + lr;
      gld_lds16(vtb + (size_t)(h * 192 + vr) * 3072 + bT + s0 + lcx * 8,
                (ushort*)(smem + kc * 1024) + lane * 8);
    }
    __syncthreads();

    // ---- PV phase ----
    short8 afr[2];
#pragma unroll
    for (int ks = 0; ks < 2; ks++)
      afr[ks] = *(const short8*)(Pp + ln * 72 + quad * 8 + ks * 32);
#pragma unroll
    for (int vt = 0; vt < 12; vt++) {
#pragma unroll
      for (int ks = 0; ks < 2; ks++) {
        short8 bfr = *(const short8*)(
            Vl + (16 * vt + ln) * 64 + ((quad + 4 * ks) ^ (ln & 7)) * 8);
        Oacc[vt] = __builtin_amdgcn_mfma_f32_16x16x32_bf16(afr[ks], bfr, Oacc[vt], 0, 0, 0);
      }
    }
  }

  // epilogue: normalized bf16 partial + (m,l)
  ushort* op = sk ? op1 : op0;
  float inv[4];
#pragma unroll
  for (int r = 0; r < 4; r++) inv[r] = 1.f / l_i[r];
#pragma unroll
  for (int vt = 0; vt < 12; vt++)
#pragma unroll
    for (int r = 0; r < 4; r++) {
      int t = t0 + 16 * w + 4 * quad + r;
      op[(size_t)(bT + t) * 1536 + h * 192 + 16 * vt + ln] = f2bs(Oacc[vt][r] * inv[r]);
    }
  if (ln == 0) {
#pragma unroll
    for (int r = 0; r < 4; r++) {
      int t = t0 + 16 * w + 4 * quad + r;
      float2 v; v.x = m_i[r]; v.y = l_i[r];
      mlb[((sk * 2 + b) * 8 + h) * 1536 + t] = v;
    }
  }
}

// ---------------------------------------------------------------------------
// Combine the two split-K partials: O = sum_i e^{m_i-M} l_i O_i / sum e^{m-M} l
// ---------------------------------------------------------------------------
__global__ __launch_bounds__(256) void attn_combine(
    const ushort* __restrict__ op0, const ushort* __restrict__ op1,
    const float2* __restrict__ mlb, ushort* __restrict__ att) {
  int g = blockIdx.x * 256 + threadIdx.x;   // group of 4 bf16
  int row = g / 384;                        // 0..3071
  int c4 = (g - row * 384) * 4;             // 0..1532
  int b = row >= 1536;
  int t = row - b * 1536;
  int h = c4 / 192;
  float2 ml0 = mlb[((0 + b) * 8 + h) * 1536 + t];
  float2 ml1 = mlb[((2 + b) * 8 + h) * 1536 + t];
  float M = fmaxf(ml0.x, ml1.x);
  float w0 = __expf(ml0.x - M) * ml0.y;
  float w1 = __expf(ml1.x - M) * ml1.y;
  float inv = 1.f / (w0 + w1);
  w0 *= inv; w1 *= inv;
  size_t off = (size_t)row * 1536 + c4;
  uint2 a = *(const uint2*)(op0 + off);
  uint2 c = *(const uint2*)(op1 + off);
  uint2 o;
  float r0 = w0 * bs2f((ushort)(a.x & 0xffff)) + w1 * bs2f((ushort)(c.x & 0xffff));
  float r1 = w0 * bs2f((ushort)(a.x >> 16))    + w1 * bs2f((ushort)(c.x >> 16));
  float r2 = w0 * bs2f((ushort)(a.y & 0xffff)) + w1 * bs2f((ushort)(c.y & 0xffff));
  float r3 = w0 * bs2f((ushort)(a.y >> 16))    + w1 * bs2f((ushort)(c.y >> 16));
  o.x = (uint)f2bs(r0) | ((uint)f2bs(r1) << 16);
  o.y = (uint)f2bs(r2) | ((uint)f2bs(r3) << 16);
  *(uint2*)(att + off) = o;
}

// ---------------------------------------------------------------------------
extern "C" void kernel_launch(void* const* d_in, const int* in_sizes, int n_in,
                              void* d_out, int out_size, void* d_ws, size_t ws_size,
                              hipStream_t stream) {
  const float* x   = (const float*)d_in[0];
  const float* Wq  = (const float*)d_in[1];
  const float* Wk  = (const float*)d_in[2];
  const float* Wv  = (const float*)d_in[3];
  const float* Wr  = (const float*)d_in[4];
  const float* rwb = (const float*)d_in[5];
  const float* rrb = (const float*)d_in[6];
  const float* Wo  = (const float*)d_in[7];
  const float* bo  = (const float*)d_in[8];
  float* out = (float*)d_out;

  char* ws = (char*)d_ws;
  // Region A [0, 9437184): xb (prep->qkv) -> op1 (attn) -> att (combine, same
  // addresses elementwise) -> gemm_out input.
  ushort* xb  = (ushort*)ws;
  ushort* op1 = (ushort*)ws;
  ushort* att = (ushort*)ws;
  ushort* Wot = (ushort*)(ws + 9437184);    // [1536][1536] bf16, until gemm_out
  ushort* Wt  = (ushort*)(ws + 14155776);   // [2560][1536] bf16, until gemm_qkv
  ushort* op0 = (ushort*)(ws + 14155776);   // overlays dead Wt (attn phase)
  ushort* qb  = (ushort*)(ws + 23592960);   // [3072][512] bf16 (scaled)
  ushort* kb  = (ushort*)(ws + 26738688);   // [3072][512] bf16
  ushort* vtb = (ushort*)(ws + 29884416);   // [1536][3072] bf16 (V^T)
  ushort* rkb = (ushort*)(ws + 39321600);   // [3071][512] bf16
  float2* mlb = (float2*)(ws + 42467328);   // [2][2][8][1536] (m,l)

  prep<<<dim3(48, 48, 6), dim3(256), 0, stream>>>(
      x, Wq, Wk, Wv, Wo, Wr, xb, Wt, Wot, rkb);
  gemm_qkv<<<dim3(20, 24), dim3(256), 0, stream>>>(xb, Wt, qb, kb, vtb);
  attn_mfma<<<dim3(24, 8, 4), dim3(256), 0, stream>>>(
      qb, kb, vtb, rkb, rwb, rrb, op0, op1, mlb);
  attn_combine<<<dim3(4608), dim3(256), 0, stream>>>(op0, op1, mlb, att);
  gemm_out<<<dim3(12, 24), dim3(256), 0, stream>>>(att, Wot, bo, out);
}

// Round 8
// 249.370 us; speedup vs baseline: 1.4826x; 1.2623x over previous
//
#include <hip/hip_runtime.h>
#include <hip/hip_bf16.h>

typedef __hip_bfloat16 bf16;
typedef unsigned short ushort;
typedef unsigned int uint;
typedef __attribute__((ext_vector_type(8))) short short8;
typedef __attribute__((ext_vector_type(4))) float f32x4;

#define Bsz 2
#define Tn  1536
#define Cn  1536
#define Hn  8
#define Kn  64
#define Vn  192
// H*K = 512, H*V = 1536, 2T-1 = 3071

__device__ __forceinline__ ushort f2bs(float f) {
  union { bf16 h; ushort u; } cv;
  cv.h = __float2bfloat16(f);
  return cv.u;
}
__device__ __forceinline__ float bs2f(ushort u) {
  union { float f; uint v; } cv; cv.v = ((uint)u) << 16; return cv.f;
}

// async global->LDS, 16B per lane; LDS dest = wave-uniform base + lane*16
__device__ __forceinline__ void gld_lds16(const ushort* g, ushort* l) {
  __builtin_amdgcn_global_load_lds(
      (const __attribute__((address_space(1))) uint*)g,
      (__attribute__((address_space(3))) uint*)l, 16, 0, 0);
}

// ---------------------------------------------------------------------------
// Merged prep kernel, grid (48,48,6):
//  z=0..3: transpose+cvt  W{q,k,v,o} f32 [1536][Cc] -> bf16 [Cc][1536]
//  z=4   : x f32 -> xb bf16 (vectorized x4, grid-stride)
//  z=5   : rk[r,c] bf16 from the Borzoi central-mask basis (double widths;
//          margins to integers >= 0.02 so no comparison flips vs fp32 ref).
// ---------------------------------------------------------------------------
__global__ __launch_bounds__(256) void prep(
    const float* __restrict__ x,  const float* __restrict__ Wq,
    const float* __restrict__ Wk, const float* __restrict__ Wv,
    const float* __restrict__ Wo, const float* __restrict__ Wr,
    ushort* __restrict__ xb, ushort* __restrict__ Wt,
    ushort* __restrict__ Wot, ushort* __restrict__ rkb) {
  const int z = blockIdx.z;
  if (z < 4) {
    if (z < 2 && blockIdx.x >= 16) return;
    const float* in = (z == 0) ? Wq : (z == 1) ? Wk : (z == 2) ? Wv : Wo;
    ushort* out = (z == 0) ? Wt : (z == 1) ? Wt + 512 * 1536
                : (z == 2) ? Wt + 1024 * 1536 : Wot;
    const int Cc = (z < 2) ? 512 : 1536;
    __shared__ float tile[32][33];
    const int bx = blockIdx.x * 32;
    const int by = blockIdx.y * 32;
    const int tx = threadIdx.x & 31, ty = threadIdx.x >> 5;
#pragma unroll
    for (int i = 0; i < 32; i += 8)
      tile[ty + i][tx] = in[(size_t)(by + ty + i) * Cc + bx + tx];
    __syncthreads();
#pragma unroll
    for (int i = 0; i < 32; i += 8)
      out[(size_t)(bx + ty + i) * 1536 + by + tx] = f2bs(tile[tx][ty + i]);
  } else if (z == 4) {
    const int n4 = 3072 * 1536 / 4;
    for (int i = (blockIdx.y * 48 + blockIdx.x) * 256 + threadIdx.x; i < n4;
         i += 2304 * 256) {
      float4 v = ((const float4*)x)[i];
      uint2 o;
      o.x = (uint)f2bs(v.x) | ((uint)f2bs(v.y) << 16);
      o.y = (uint)f2bs(v.z) | ((uint)f2bs(v.w) << 16);
      ((uint2*)xb)[i] = o;
    }
  } else {
    for (int u = blockIdx.y * 48 + blockIdx.x; u < 2 * 3071; u += 2304) {
      const int r = u >> 1;
      const int c = (u & 1) * 256 + threadIdx.x;
      const float d = (float)(r - (Tn - 1));
      const float ad = fabsf(d);
      const float sg = (d > 0.f) ? 1.f : ((d < 0.f) ? -1.f : 0.f);
      float acc = 0.f;
#pragma unroll
      for (int i = 0; i < 16; i++) {
        double cw = exp(log((double)(Tn + 1)) * (double)(i + 1) / 16.0) - 1.0;
        if ((float)cw > ad) acc += Wr[i * 512 + c] + sg * Wr[(16 + i) * 512 + c];
      }
      rkb[(size_t)r * 512 + c] = f2bs(acc);
    }
  }
}

// ---------------------------------------------------------------------------
// Fused QKV MFMA GEMM: xb @ Wt^T-layout -> qb/kb/vtb (m97 structure).
// ---------------------------------------------------------------------------
__global__ __launch_bounds__(256) void gemm_qkv(
    const ushort* __restrict__ xb, const ushort* __restrict__ Wt,
    ushort* __restrict__ qb, ushort* __restrict__ kb, ushort* __restrict__ vtb) {
  __shared__ ushort Al[128 * 32];
  __shared__ ushort Bl[128 * 32];
  const int tid = threadIdx.x;
  const int w = tid >> 6, lane = tid & 63, quad = lane >> 4, ln = lane & 15;
  const int bm = blockIdx.y * 128, bn = blockIdx.x * 128;
  const int wm = (w & 1) * 64, wn = (w >> 1) * 64;
  f32x4 acc[4][4];
#pragma unroll
  for (int i = 0; i < 4; i++)
#pragma unroll
    for (int j = 0; j < 4; j++) acc[i][j] = (f32x4){0.f, 0.f, 0.f, 0.f};

  for (int k0 = 0; k0 < 1536; k0 += 32) {
    __syncthreads();
#pragma unroll
    for (int st = 0; st < 2; st++) {
      int idx = tid + st * 256;
      int row = idx >> 2, col = (idx & 3) * 8;
      gld_lds16(xb + (size_t)(bm + row) * 1536 + k0 + col, Al + idx * 8);
      gld_lds16(Wt + (size_t)(bn + row) * 1536 + k0 + col, Bl + idx * 8);
    }
    __syncthreads();
    short8 af[4], bfr[4];
#pragma unroll
    for (int t = 0; t < 4; t++) {
      af[t]  = *(const short8*)(Al + (wm + t * 16 + ln) * 32 + quad * 8);
      bfr[t] = *(const short8*)(Bl + (wn + t * 16 + ln) * 32 + quad * 8);
    }
#pragma unroll
    for (int mt = 0; mt < 4; mt++)
#pragma unroll
      for (int nt = 0; nt < 4; nt++)
        acc[mt][nt] = __builtin_amdgcn_mfma_f32_16x16x32_bf16(
            af[mt], bfr[nt], acc[mt][nt], 0, 0, 0);
  }

  if (bn < 512) {
#pragma unroll
    for (int mt = 0; mt < 4; mt++)
#pragma unroll
      for (int nt = 0; nt < 4; nt++)
#pragma unroll
        for (int r = 0; r < 4; r++) {
          int m = bm + wm + mt * 16 + quad * 4 + r;
          int n = bn + wn + nt * 16 + ln;
          qb[(size_t)m * 512 + n] = f2bs(acc[mt][nt][r] * 0.125f);
        }
  } else if (bn < 1024) {
#pragma unroll
    for (int mt = 0; mt < 4; mt++)
#pragma unroll
      for (int nt = 0; nt < 4; nt++)
#pragma unroll
        for (int r = 0; r < 4; r++) {
          int m = bm + wm + mt * 16 + quad * 4 + r;
          int n = bn - 512 + wn + nt * 16 + ln;
          kb[(size_t)m * 512 + n] = f2bs(acc[mt][nt][r]);
        }
  } else {
#pragma unroll
    for (int mt = 0; mt < 4; mt++)
#pragma unroll
      for (int nt = 0; nt < 4; nt++) {
        int vcol = bn - 1024 + wn + nt * 16 + ln;
        int m0 = bm + wm + mt * 16 + quad * 4;
        uint2 val;
        val.x = (uint)f2bs(acc[mt][nt][0]) | ((uint)f2bs(acc[mt][nt][1]) << 16);
        val.y = (uint)f2bs(acc[mt][nt][2]) | ((uint)f2bs(acc[mt][nt][3]) << 16);
        *(uint2*)(vtb + (size_t)vcol * 3072 + m0) = val;
      }
  }
}

// ---------------------------------------------------------------------------
// Output MFMA GEMM: att(bf16) @ Wot + bo -> f32 out.
// ---------------------------------------------------------------------------
__global__ __launch_bounds__(256) void gemm_out(
    const ushort* __restrict__ att, const ushort* __restrict__ Wot,
    const float* __restrict__ bo, float* __restrict__ out) {
  __shared__ ushort Al[128 * 32];
  __shared__ ushort Bl[128 * 32];
  const int tid = threadIdx.x;
  const int w = tid >> 6, lane = tid & 63, quad = lane >> 4, ln = lane & 15;
  const int bm = blockIdx.y * 128, bn = blockIdx.x * 128;
  const int wm = (w & 1) * 64, wn = (w >> 1) * 64;
  f32x4 acc[4][4];
#pragma unroll
  for (int i = 0; i < 4; i++)
#pragma unroll
    for (int j = 0; j < 4; j++) acc[i][j] = (f32x4){0.f, 0.f, 0.f, 0.f};

  for (int k0 = 0; k0 < 1536; k0 += 32) {
    __syncthreads();
#pragma unroll
    for (int st = 0; st < 2; st++) {
      int idx = tid + st * 256;
      int row = idx >> 2, col = (idx & 3) * 8;
      gld_lds16(att + (size_t)(bm + row) * 1536 + k0 + col, Al + idx * 8);
      gld_lds16(Wot + (size_t)(bn + row) * 1536 + k0 + col, Bl + idx * 8);
    }
    __syncthreads();
    short8 af[4], bfr[4];
#pragma unroll
    for (int t = 0; t < 4; t++) {
      af[t]  = *(const short8*)(Al + (wm + t * 16 + ln) * 32 + quad * 8);
      bfr[t] = *(const short8*)(Bl + (wn + t * 16 + ln) * 32 + quad * 8);
    }
#pragma unroll
    for (int mt = 0; mt < 4; mt++)
#pragma unroll
      for (int nt = 0; nt < 4; nt++)
        acc[mt][nt] = __builtin_amdgcn_mfma_f32_16x16x32_bf16(
            af[mt], bfr[nt], acc[mt][nt], 0, 0, 0);
  }
#pragma unroll
  for (int mt = 0; mt < 4; mt++)
#pragma unroll
    for (int nt = 0; nt < 4; nt++)
#pragma unroll
      for (int r = 0; r < 4; r++) {
        int m = bm + wm + mt * 16 + quad * 4 + r;
        int n = bn + wn + nt * 16 + ln;
        out[(size_t)m * 1536 + n] = acc[mt][nt][r] + bo[n];
      }
}

// ---------------------------------------------------------------------------
// MFMA flash attention, split-K(x2), t-tile 64, 4 waves, DMA staging.
// XCD-AWARE SWIZZLE: linear block id L -> xcd = L&7 owns head h = xcd only.
//   g = L>>3; bsk = g/24 (b = bsk>>1, sk = bsk&1); t0 = (g%24)*64.
// Per-XCD L2 working set = one head's kb/vtb/rkb/qb slices (~2.4 MB < 4 MiB).
// LDS [38912B]: K[64]x128B @0, RK[128]x128B @8192 (V[192]x128B overlays);
//   per-wave 3584B scratch @24576: prl bf16[16][104] overlaid by Pp bf16[16][72].
// XOR swizzle: 16B chunk c of row r stored at physical chunk c^(r&7).
// Rel: j = (s-s0)-(t-t0)+63 in [0,127); wave w needs j-tiles 3-w..7-w (5).
// Partials: normalized O (bf16) + (m,l) per row; combined by attn_combine.
// ---------------------------------------------------------------------------
__global__ __launch_bounds__(256, 3) void attn_mfma(
    const ushort* __restrict__ qb, const ushort* __restrict__ kb,
    const ushort* __restrict__ vtb, const ushort* __restrict__ rkb,
    const float* __restrict__ rwb, const float* __restrict__ rrb,
    ushort* __restrict__ op0, ushort* __restrict__ op1,
    float2* __restrict__ mlb) {
  __shared__ __align__(16) char smem[38912];
  ushort* Kl  = (ushort*)smem;              // [64] rows x 128B
  ushort* RKl = (ushort*)(smem + 8192);     // [128] rows x 128B
  ushort* Vl  = (ushort*)smem;              // [192] rows x 128B (overlay)

  const int L  = blockIdx.x + 24 * blockIdx.y + 192 * blockIdx.z;
  const int h  = L & 7;                     // XCD id under round-robin
  const int g  = L >> 3;
  const int bsk = g / 24;
  const int b  = bsk >> 1;
  const int sk = bsk & 1;
  const int t0 = (g - bsk * 24) * 64;
  const int bT = b * Tn;
  const int tid = threadIdx.x;
  const int w = tid >> 6, lane = tid & 63, quad = lane >> 4, ln = lane & 15;

  ushort* prlb = (ushort*)(smem + 24576 + w * 3584);  // [16][104] bf16
  ushort* Pp   = (ushort*)(smem + 24576 + w * 3584);  // [16][72] bf16 (overlay)

  const int lr  = lane >> 3;          // staging: row-in-chunk 0..7
  const int lcx = (lane & 7) ^ lr;    // staging: logical 16B chunk (swizzle)

  // Q fragments (A-layout m=ln, k=quad*8+ks*32+e), + biases
  short8 qw8[2], qr8[2];
  {
    const ushort* qrow = qb + (size_t)(bT + t0 + 16 * w + ln) * 512 + h * 64;
#pragma unroll
    for (int ks = 0; ks < 2; ks++) {
      int k0 = quad * 8 + ks * 32;
#pragma unroll
      for (int e = 0; e < 8; e++) {
        float qv = bs2f(qrow[k0 + e]);
        qw8[ks][e] = (short)f2bs(qv + rwb[h * 64 + k0 + e]);
        qr8[ks][e] = (short)f2bs(qv + rrb[h * 64 + k0 + e]);
      }
    }
  }

  f32x4 Oacc[12];
  float m_i[4], l_i[4];
#pragma unroll
  for (int vt = 0; vt < 12; vt++) Oacc[vt] = (f32x4){0.f, 0.f, 0.f, 0.f};
#pragma unroll
  for (int r = 0; r < 4; r++) { m_i[r] = -1e30f; l_i[r] = 0.f; }

  for (int ch = 0; ch < 12; ch++) {
    const int s0 = sk * 768 + ch * 64;
    const int Dbase = s0 - t0 + 1472;
    __syncthreads();   // prev PV done reading Vl (overlay with K/RK)
    // stage K (8 KB, 8 chunks of 1KB; 2 per wave)
#pragma unroll
    for (int i = 0; i < 2; i++) {
      int kc = w * 2 + i, sr = kc * 8 + lr;
      gld_lds16(kb + (size_t)(bT + s0 + sr) * 512 + h * 64 + lcx * 8,
                (ushort*)(smem + kc * 1024) + lane * 8);
    }
    // stage RK (16 KB, 16 chunks; 4 per wave). j=127 unused -> clamp.
#pragma unroll
    for (int i = 0; i < 4; i++) {
      int kc = w * 4 + i, j = kc * 8 + lr;
      int jr = Dbase + j; jr = jr > 3070 ? 3070 : jr;
      gld_lds16(rkb + (size_t)jr * 512 + h * 64 + lcx * 8,
                (ushort*)(smem + 8192 + kc * 1024) + lane * 8);
    }
    __syncthreads();

    // ---- S phase ----
    f32x4 Sacc[4], Pacc[5];
#pragma unroll
    for (int ct = 0; ct < 4; ct++) {
      Sacc[ct] = (f32x4){0.f, 0.f, 0.f, 0.f};
#pragma unroll
      for (int ks = 0; ks < 2; ks++) {
        short8 bfr = *(const short8*)(
            Kl + (16 * ct + ln) * 64 + ((quad + 4 * ks) ^ (ln & 7)) * 8);
        Sacc[ct] = __builtin_amdgcn_mfma_f32_16x16x32_bf16(qw8[ks], bfr, Sacc[ct], 0, 0, 0);
      }
    }
#pragma unroll
    for (int jtl = 0; jtl < 5; jtl++) {
      int jt = 3 - w + jtl;
      Pacc[jtl] = (f32x4){0.f, 0.f, 0.f, 0.f};
#pragma unroll
      for (int ks = 0; ks < 2; ks++) {
        short8 bfr = *(const short8*)(
            RKl + (16 * jt + ln) * 64 + ((quad + 4 * ks) ^ (ln & 7)) * 8);
        Pacc[jtl] = __builtin_amdgcn_mfma_f32_16x16x32_bf16(qr8[ks], bfr, Pacc[jtl], 0, 0, 0);
      }
    }
    // rel logits (C-layout) -> per-wave prl (bf16); local col jl = 16*jtl + ln
#pragma unroll
    for (int jtl = 0; jtl < 5; jtl++)
#pragma unroll
      for (int r = 0; r < 4; r++)
        prlb[(4 * quad + r) * 104 + 16 * jtl + ln] = f2bs(Pacc[jtl][r]);
    __asm__ volatile("s_waitcnt lgkmcnt(0)" ::: "memory");

    // gather: jl = 16ct + ln - row + 15 (row = wave-local q-row)
    float pS[4][4];
#pragma unroll
    for (int ct = 0; ct < 4; ct++)
#pragma unroll
      for (int r = 0; r < 4; r++) {
        int row = 4 * quad + r;
        pS[ct][r] = Sacc[ct][r] + bs2f(prlb[row * 104 + 16 * ct + ln - row + 15]);
      }
    // online softmax (row lives in the 16 lanes of this quad)
    float alpha[4];
#pragma unroll
    for (int r = 0; r < 4; r++) {
      float mx = fmaxf(fmaxf(pS[0][r], pS[1][r]), fmaxf(pS[2][r], pS[3][r]));
#pragma unroll
      for (int off = 8; off >= 1; off >>= 1) mx = fmaxf(mx, __shfl_xor(mx, off));
      float mnew = fmaxf(m_i[r], mx);
      alpha[r] = __expf(m_i[r] - mnew);
      m_i[r] = mnew;
      float rs = 0.f;
#pragma unroll
      for (int ct = 0; ct < 4; ct++) {
        pS[ct][r] = __expf(pS[ct][r] - mnew);
        rs += pS[ct][r];
      }
#pragma unroll
      for (int off = 8; off >= 1; off >>= 1) rs += __shfl_xor(rs, off);
      l_i[r] = l_i[r] * alpha[r] + rs;
    }
#pragma unroll
    for (int vt = 0; vt < 12; vt++)
#pragma unroll
      for (int r = 0; r < 4; r++) Oacc[vt][r] *= alpha[r];
    // probs -> Pp (bf16, overlays prl; all prl reads precede, same wave = safe)
#pragma unroll
    for (int ct = 0; ct < 4; ct++)
#pragma unroll
      for (int r = 0; r < 4; r++)
        Pp[(4 * quad + r) * 72 + 16 * ct + ln] = f2bs(pS[ct][r]);

    __syncthreads();   // all waves done with K/RK
    // stage V (24 KB, 24 chunks; 6 per wave) over K+RK region
#pragma unroll
    for (int i = 0; i < 6; i++) {
      int kc = w * 6 + i, vr = kc * 8 + lr;
      gld_lds16(vtb + (size_t)(h * 192 + vr) * 3072 + bT + s0 + lcx * 8,
                (ushort*)(smem + kc * 1024) + lane * 8);
    }
    __syncthreads();

    // ---- PV phase ----
    short8 afr[2];
#pragma unroll
    for (int ks = 0; ks < 2; ks++)
      afr[ks] = *(const short8*)(Pp + ln * 72 + quad * 8 + ks * 32);
#pragma unroll
    for (int vt = 0; vt < 12; vt++) {
#pragma unroll
      for (int ks = 0; ks < 2; ks++) {
        short8 bfr = *(const short8*)(
            Vl + (16 * vt + ln) * 64 + ((quad + 4 * ks) ^ (ln & 7)) * 8);
        Oacc[vt] = __builtin_amdgcn_mfma_f32_16x16x32_bf16(afr[ks], bfr, Oacc[vt], 0, 0, 0);
      }
    }
  }

  // epilogue: normalized bf16 partial + (m,l)
  ushort* op = sk ? op1 : op0;
  float inv[4];
#pragma unroll
  for (int r = 0; r < 4; r++) inv[r] = 1.f / l_i[r];
#pragma unroll
  for (int vt = 0; vt < 12; vt++)
#pragma unroll
    for (int r = 0; r < 4; r++) {
      int t = t0 + 16 * w + 4 * quad + r;
      op[(size_t)(bT + t) * 1536 + h * 192 + 16 * vt + ln] = f2bs(Oacc[vt][r] * inv[r]);
    }
  if (ln == 0) {
#pragma unroll
    for (int r = 0; r < 4; r++) {
      int t = t0 + 16 * w + 4 * quad + r;
      float2 v; v.x = m_i[r]; v.y = l_i[r];
      mlb[((sk * 2 + b) * 8 + h) * 1536 + t] = v;
    }
  }
}

// ---------------------------------------------------------------------------
// Combine the two split-K partials: O = sum_i e^{m_i-M} l_i O_i / sum e^{m-M} l
// ---------------------------------------------------------------------------
__global__ __launch_bounds__(256) void attn_combine(
    const ushort* __restrict__ op0, const ushort* __restrict__ op1,
    const float2* __restrict__ mlb, ushort* __restrict__ att) {
  int g = blockIdx.x * 256 + threadIdx.x;   // group of 4 bf16
  int row = g / 384;                        // 0..3071
  int c4 = (g - row * 384) * 4;             // 0..1532
  int b = row >= 1536;
  int t = row - b * 1536;
  int h = c4 / 192;
  float2 ml0 = mlb[((0 + b) * 8 + h) * 1536 + t];
  float2 ml1 = mlb[((2 + b) * 8 + h) * 1536 + t];
  float M = fmaxf(ml0.x, ml1.x);
  float w0 = __expf(ml0.x - M) * ml0.y;
  float w1 = __expf(ml1.x - M) * ml1.y;
  float inv = 1.f / (w0 + w1);
  w0 *= inv; w1 *= inv;
  size_t off = (size_t)row * 1536 + c4;
  uint2 a = *(const uint2*)(op0 + off);
  uint2 c = *(const uint2*)(op1 + off);
  uint2 o;
  float r0 = w0 * bs2f((ushort)(a.x & 0xffff)) + w1 * bs2f((ushort)(c.x & 0xffff));
  float r1 = w0 * bs2f((ushort)(a.x >> 16))    + w1 * bs2f((ushort)(c.x >> 16));
  float r2 = w0 * bs2f((ushort)(a.y & 0xffff)) + w1 * bs2f((ushort)(c.y & 0xffff));
  float r3 = w0 * bs2f((ushort)(a.y >> 16))    + w1 * bs2f((ushort)(c.y >> 16));
  o.x = (uint)f2bs(r0) | ((uint)f2bs(r1) << 16);
  o.y = (uint)f2bs(r2) | ((uint)f2bs(r3) << 16);
  *(uint2*)(att + off) = o;
}

// ---------------------------------------------------------------------------
extern "C" void kernel_launch(void* const* d_in, const int* in_sizes, int n_in,
                              void* d_out, int out_size, void* d_ws, size_t ws_size,
                              hipStream_t stream) {
  const float* x   = (const float*)d_in[0];
  const float* Wq  = (const float*)d_in[1];
  const float* Wk  = (const float*)d_in[2];
  const float* Wv  = (const float*)d_in[3];
  const float* Wr  = (const float*)d_in[4];
  const float* rwb = (const float*)d_in[5];
  const float* rrb = (const float*)d_in[6];
  const float* Wo  = (const float*)d_in[7];
  const float* bo  = (const float*)d_in[8];
  float* out = (float*)d_out;

  char* ws = (char*)d_ws;
  // Region A [0, 9437184): xb (prep->qkv) -> op1 (attn) -> att (combine, same
  // addresses elementwise) -> gemm_out input.
  ushort* xb  = (ushort*)ws;
  ushort* op1 = (ushort*)ws;
  ushort* att = (ushort*)ws;
  ushort* Wot = (ushort*)(ws + 9437184);    // [1536][1536] bf16, until gemm_out
  ushort* Wt  = (ushort*)(ws + 14155776);   // [2560][1536] bf16, until gemm_qkv
  ushort* op0 = (ushort*)(ws + 14155776);   // overlays dead Wt (attn phase)
  ushort* qb  = (ushort*)(ws + 23592960);   // [3072][512] bf16 (scaled)
  ushort* kb  = (ushort*)(ws + 26738688);   // [3072][512] bf16
  ushort* vtb = (ushort*)(ws + 29884416);   // [1536][3072] bf16 (V^T)
  ushort* rkb = (ushort*)(ws + 39321600);   // [3071][512] bf16
  float2* mlb = (float2*)(ws + 42467328);   // [2][2][8][1536] (m,l)

  prep<<<dim3(48, 48, 6), dim3(256), 0, stream>>>(
      x, Wq, Wk, Wv, Wo, Wr, xb, Wt, Wot, rkb);
  gemm_qkv<<<dim3(20, 24), dim3(256), 0, stream>>>(xb, Wt, qb, kb, vtb);
  attn_mfma<<<dim3(24, 8, 4), dim3(256), 0, stream>>>(
      qb, kb, vtb, rkb, rwb, rrb, op0, op1, mlb);
  attn_combine<<<dim3(4608), dim3(256), 0, stream>>>(op0, op1, mlb, att);
  gemm_out<<<dim3(12, 24), dim3(256), 0, stream>>>(att, Wot, bo, out);
}